// Round 5
// baseline (411.318 us; speedup 1.0000x reference)
//
#include <hip/hip_runtime.h>

#define N_NODES 50000
#define N_EDGES 800000
#define NF 128
#define N_GRAPHS 512
#define SCAN_BLOCKS 196   // ceil(50000/256)
#define PCHUNK 512        // edges per pool_partial block

union HU { ushort u; _Float16 h; };
__device__ __forceinline__ float h2f(ushort u) { HU x; x.u = u; return (float)x.h; }
__device__ __forceinline__ ushort f2h(float f) { HU x; x.h = (_Float16)f; return x.u; }

__device__ __forceinline__ void acc8(float* acc, uint4 u) {
  acc[0] += h2f((ushort)(u.x)); acc[1] += h2f((ushort)(u.x >> 16));
  acc[2] += h2f((ushort)(u.y)); acc[3] += h2f((ushort)(u.y >> 16));
  acc[4] += h2f((ushort)(u.z)); acc[5] += h2f((ushort)(u.z >> 16));
  acc[6] += h2f((ushort)(u.w)); acc[7] += h2f((ushort)(u.w >> 16));
}

// ---------------- x (f32) -> xh (fp16) ---------------------------------------
__global__ __launch_bounds__(256) void xcvt(const float* __restrict__ x,
                                            ushort* __restrict__ xh) {
  int i = blockIdx.x * 256 + threadIdx.x;
  float4 v = ((const float4*)x)[i];
  ushort4 o;
  o.x = f2h(v.x); o.y = f2h(v.y); o.z = f2h(v.z); o.w = f2h(v.w);
  ((ushort4*)xh)[i] = o;
}

// ---------------- v[f] = sum_j W2[f][j] * Wfc[j] ------------------------------
__global__ __launch_bounds__(128) void w2wfc(const float* __restrict__ W2,
                                             const float* __restrict__ Wfc,
                                             float* __restrict__ v) {
  int f = threadIdx.x;
  float s = 0.f;
  for (int j = 0; j < 128; j += 4) {
    float4 w = ((const float4*)(W2 + f * 128))[j >> 2];
    float4 c = ((const float4*)Wfc)[j >> 2];
    s += w.x * c.x + w.y * c.y + w.z * c.z + w.w * c.w;
  }
  v[f] = s;
}

// ---------------- CSR build: dst -> list of src ------------------------------
__global__ __launch_bounds__(256) void hist_kernel(const int* __restrict__ dst,
                                                   int* __restrict__ deg) {
  unsigned e = blockIdx.x * 256u + threadIdx.x;
  if (e < N_EDGES) atomicAdd(&deg[dst[e]], 1);
}

__device__ __forceinline__ int block_incl_scan_256(int v, int* warp_sums) {
  const int tid = threadIdx.x;
  const int lane = tid & 63;
  const int w = tid >> 6;
#pragma unroll
  for (int off = 1; off < 64; off <<= 1) {
    int t = __shfl_up(v, off, 64);
    if (lane >= off) v += t;
  }
  if (lane == 63) warp_sums[w] = v;
  __syncthreads();
  int ws = 0;
#pragma unroll
  for (int i = 0; i < 4; ++i) ws += (i < w) ? warp_sums[i] : 0;
  return v + ws;
}

__global__ __launch_bounds__(256) void scan_stage1(const int* __restrict__ deg,
                                                   int* __restrict__ rowptr,
                                                   int* __restrict__ blocksum) {
  __shared__ int warp_sums[4];
  int i = blockIdx.x * 256 + threadIdx.x;
  int v = (i < N_NODES) ? deg[i] : 0;
  int incl = block_incl_scan_256(v, warp_sums);
  if (i < N_NODES) rowptr[i + 1] = incl;
  if (threadIdx.x == 255) blocksum[blockIdx.x] = incl;
}

__global__ __launch_bounds__(256) void scan_stage2(int* __restrict__ blocksum) {
  __shared__ int warp_sums[4];
  int tid = threadIdx.x;
  int v = (tid < SCAN_BLOCKS) ? blocksum[tid] : 0;
  int incl = block_incl_scan_256(v, warp_sums);
  if (tid < SCAN_BLOCKS) blocksum[tid] = incl - v;
}

__global__ __launch_bounds__(256) void scan_stage3(int* __restrict__ rowptr,
                                                   const int* __restrict__ blocksum,
                                                   int* __restrict__ cursor) {
  int i = blockIdx.x * 256 + threadIdx.x;
  if (i < N_NODES) {
    int r = rowptr[i + 1] + blocksum[blockIdx.x];
    rowptr[i + 1] = r;
    cursor[i + 1] = r;
  }
  if (i == 0) { rowptr[0] = 0; cursor[0] = 0; }
}

// fill CSR col + per-edge graph id (batch[dst] — non-decreasing in CSR order)
__global__ __launch_bounds__(256) void fill_kernel(const int* __restrict__ src,
                                                   const int* __restrict__ dst,
                                                   const int* __restrict__ batch,
                                                   int* __restrict__ cursor,
                                                   int* __restrict__ col,
                                                   ushort* __restrict__ egid) {
  unsigned e = blockIdx.x * 256u + threadIdx.x;
  if (e < N_EDGES) {
    int d = dst[e];
    int pos = atomicAdd(&cursor[d], 1);
    col[pos] = src[e];
    egid[pos] = (ushort)batch[d];
  }
}

// ------- fused conv1: hA = relu( (gather xh) @ W1 ) as fp16 -------------------
// block = 64 output rows; gather phase sums neighbor fp16 rows into sA (f32),
// then the LDS-tiled K-loop multiplies by W1.
__global__ __launch_bounds__(256) void gather_gemm_relu(
    const ushort* __restrict__ xh, const int* __restrict__ rowptr,
    const int* __restrict__ col, const float* __restrict__ W,
    ushort* __restrict__ hA, int M) {
  __shared__ float sA[64][132];
  __shared__ float sW[32][128];
  const int tid = threadIdx.x;
  const int row0 = blockIdx.x * 64;

  // ---- gather phase: 16 node-lanes x 16 q-lanes (uint4 = 8 feats), 4 rounds
  {
    const int q = tid & 15;
    const int nl = tid >> 4;
#pragma unroll
    for (int r = 0; r < 4; ++r) {
      int node = row0 + r * 16 + nl;
      float acc[8] = {0.f, 0.f, 0.f, 0.f, 0.f, 0.f, 0.f, 0.f};
      if (node < M) {
        int j0 = rowptr[node], j1 = rowptr[node + 1];
        int j = j0;
        for (; j + 2 <= j1; j += 2) {
          int s0 = col[j], s1 = col[j + 1];
          uint4 u0 = ((const uint4*)xh)[(size_t)s0 * 16 + q];
          uint4 u1 = ((const uint4*)xh)[(size_t)s1 * 16 + q];
          acc8(acc, u0);
          acc8(acc, u1);
        }
        if (j < j1) {
          uint4 u0 = ((const uint4*)xh)[(size_t)col[j] * 16 + q];
          acc8(acc, u0);
        }
      }
      int lr = r * 16 + nl;
#pragma unroll
      for (int k = 0; k < 8; ++k) sA[lr][q * 8 + k] = acc[k];
    }
  }
  __syncthreads();

  // ---- GEMM phase ----
  const int rg = tid >> 4;   // 0..15 -> 4 rows each
  const int cg = tid & 15;   // 0..15 -> 8 cols each
  float4 acc[4][2];
#pragma unroll
  for (int i = 0; i < 4; ++i) {
    acc[i][0] = float4{0.f, 0.f, 0.f, 0.f};
    acc[i][1] = float4{0.f, 0.f, 0.f, 0.f};
  }

  for (int kt = 0; kt < 128; kt += 32) {
#pragma unroll
    for (int i = 0; i < 4; ++i) {
      int idx = i * 256 + tid;
      int r = idx >> 5, c4 = idx & 31;
      ((float4*)&sW[r][0])[c4] = ((const float4*)W)[(kt + r) * 32 + c4];
    }
    __syncthreads();

#pragma unroll
    for (int k = 0; k < 32; k += 4) {
      float4 a0 = *(const float4*)&sA[rg * 4 + 0][kt + k];
      float4 a1 = *(const float4*)&sA[rg * 4 + 1][kt + k];
      float4 a2 = *(const float4*)&sA[rg * 4 + 2][kt + k];
      float4 a3 = *(const float4*)&sA[rg * 4 + 3][kt + k];
      const float* ap0 = (const float*)&a0;
      const float* ap1 = (const float*)&a1;
      const float* ap2 = (const float*)&a2;
      const float* ap3 = (const float*)&a3;
#pragma unroll
      for (int kk = 0; kk < 4; ++kk) {
        float4 w0 = *(const float4*)&sW[k + kk][cg * 8];
        float4 w1 = *(const float4*)&sW[k + kk][cg * 8 + 4];
        float a0k = ap0[kk], a1k = ap1[kk], a2k = ap2[kk], a3k = ap3[kk];
#define FMA_ROW(I, AK)                                                         \
        acc[I][0].x += AK * w0.x; acc[I][0].y += AK * w0.y;                    \
        acc[I][0].z += AK * w0.z; acc[I][0].w += AK * w0.w;                    \
        acc[I][1].x += AK * w1.x; acc[I][1].y += AK * w1.y;                    \
        acc[I][1].z += AK * w1.z; acc[I][1].w += AK * w1.w;
        FMA_ROW(0, a0k)
        FMA_ROW(1, a1k)
        FMA_ROW(2, a2k)
        FMA_ROW(3, a3k)
#undef FMA_ROW
      }
    }
    __syncthreads();
  }

#pragma unroll
  for (int i = 0; i < 4; ++i) {
    int gr = row0 + rg * 4 + i;
    if (gr < M) {
      float4 a0 = acc[i][0], a1 = acc[i][1];
      a0.x = fmaxf(a0.x, 0.f); a0.y = fmaxf(a0.y, 0.f);
      a0.z = fmaxf(a0.z, 0.f); a0.w = fmaxf(a0.w, 0.f);
      a1.x = fmaxf(a1.x, 0.f); a1.y = fmaxf(a1.y, 0.f);
      a1.z = fmaxf(a1.z, 0.f); a1.w = fmaxf(a1.w, 0.f);
      uint4 o;
      o.x = (uint)f2h(a0.x) | ((uint)f2h(a0.y) << 16);
      o.y = (uint)f2h(a0.z) | ((uint)f2h(a0.w) << 16);
      o.z = (uint)f2h(a1.x) | ((uint)f2h(a1.y) << 16);
      o.w = (uint)f2h(a1.z) | ((uint)f2h(a1.w) << 16);
      ((uint4*)hA)[gr * 16 + cg] = o;
    }
  }
}

// ------- pool partial: pooled[g][:] += sum of hA rows of edges with egid==g --
// 16 edge-lanes x 16 q-lanes per block; egid non-decreasing along CSR order,
// so each thread flushes only at graph-run boundaries (~1-2 per thread).
__global__ __launch_bounds__(256) void pool_partial(const ushort* __restrict__ hA,
                                                    const int* __restrict__ col,
                                                    const ushort* __restrict__ egid,
                                                    float* __restrict__ pooled) {
  int j0 = blockIdx.x * PCHUNK;
  int j1 = j0 + PCHUNK; if (j1 > N_EDGES) j1 = N_EDGES;
  const int q = threadIdx.x & 15;
  const int eo = threadIdx.x >> 4;

  float acc[8] = {0.f, 0.f, 0.f, 0.f, 0.f, 0.f, 0.f, 0.f};
  int cur = -1;
  for (int j = j0 + eo; j < j1; j += 16) {
    int gid = egid[j];
    if (gid != cur) {
      if (cur >= 0) {
#pragma unroll
        for (int k = 0; k < 8; ++k) {
          unsafeAtomicAdd(&pooled[cur * NF + q * 8 + k], acc[k]);
          acc[k] = 0.f;
        }
      }
      cur = gid;
    }
    uint4 u = ((const uint4*)hA)[(size_t)col[j] * 16 + q];
    acc8(acc, u);
  }
  if (cur >= 0) {
#pragma unroll
    for (int k = 0; k < 8; ++k)
      unsafeAtomicAdd(&pooled[cur * NF + q * 8 + k], acc[k]);
  }
}

// ------- finish: z[g] = (pooled[g]/cnt[g]) . v ; out = sigmoid(z) ------------
__global__ __launch_bounds__(128) void pool_finish(const float* __restrict__ pooled,
                                                   const int* __restrict__ batch,
                                                   const float* __restrict__ v,
                                                   float* __restrict__ out) {
  __shared__ float reds[2];
  int g = blockIdx.x, f = threadIdx.x;

  int lo = 0, hi = N_NODES;
  while (lo < hi) { int m = (lo + hi) >> 1; if (batch[m] < g) lo = m + 1; else hi = m; }
  int s0 = lo;
  lo = 0; hi = N_NODES;
  while (lo < hi) { int m = (lo + hi) >> 1; if (batch[m] <= g) lo = m + 1; else hi = m; }
  int s1 = lo;

  float cnt = fmaxf((float)(s1 - s0), 1.0f);
  float z = (pooled[g * NF + f] / cnt) * v[f];
#pragma unroll
  for (int off = 32; off > 0; off >>= 1) z += __shfl_down(z, off, 64);
  if (f == 0) reds[0] = z;
  if (f == 64) reds[1] = z;
  __syncthreads();
  if (f == 0) {
    float zz = reds[0] + reds[1];
    out[g] = 1.0f / (1.0f + expf(-zz));
  }
}

extern "C" void kernel_launch(void* const* d_in, const int* in_sizes, int n_in,
                              void* d_out, int out_size, void* d_ws, size_t ws_size,
                              hipStream_t stream) {
  const float* x   = (const float*)d_in[0];
  const int*   ei  = (const int*)d_in[1];
  const int*   src = ei;               // edge_index[0]
  const int*   dst = ei + N_EDGES;     // edge_index[1]
  const int* batch = (const int*)d_in[2];
  const float* W1  = (const float*)d_in[3];
  const float* W2  = (const float*)d_in[4];
  const float* Wfc = (const float*)d_in[5];
  float* out = (float*)d_out;

  float*  pooled = (float*)d_ws;                        // 512*128 f32
  ushort* xh  = (ushort*)(pooled + N_GRAPHS * NF);      // 6.4M fp16
  ushort* hA  = xh + (size_t)N_NODES * NF;              // 6.4M fp16
  ushort* egid = hA + (size_t)N_NODES * NF;             // 800k ushort
  int* deg    = (int*)(egid + N_EDGES);
  int* rowptr = deg + N_NODES;           // N_NODES+1
  int* cursor = rowptr + N_NODES + 1;    // N_NODES+1
  int* col    = cursor + N_NODES + 1;    // N_EDGES
  int* blocksum = col + N_EDGES;         // SCAN_BLOCKS
  float* v    = (float*)(blocksum + SCAN_BLOCKS + 4);   // 128

  const int gemm_grid = (N_NODES + 63) / 64;            // 782
  const int edge_grid = (N_EDGES + 255) / 256;          // 3125
  const int cvt_grid  = (N_NODES * NF / 4) / 256;       // 6250 exact
  const int pool_grid = (N_EDGES + PCHUNK - 1) / PCHUNK; // 1563

  // --- build CSR (dst -> srcs) + per-edge graph ids ---
  hipMemsetAsync(deg, 0, N_NODES * sizeof(int), stream);
  hipMemsetAsync(pooled, 0, N_GRAPHS * NF * sizeof(float), stream);
  hist_kernel<<<edge_grid, 256, 0, stream>>>(dst, deg);
  scan_stage1<<<SCAN_BLOCKS, 256, 0, stream>>>(deg, rowptr, blocksum);
  scan_stage2<<<1, 256, 0, stream>>>(blocksum);
  scan_stage3<<<SCAN_BLOCKS, 256, 0, stream>>>(rowptr, blocksum, cursor);
  fill_kernel<<<edge_grid, 256, 0, stream>>>(src, dst, batch, cursor, col, egid);

  // --- precompute fp16 x and v = W2@Wfc ---
  xcvt<<<cvt_grid, 256, 0, stream>>>(x, xh);
  w2wfc<<<1, 128, 0, stream>>>(W2, Wfc, v);

  // --- conv1 fused: hA = relu(gather(xh) @ W1) (fp16) ---
  gather_gemm_relu<<<gemm_grid, 256, 0, stream>>>(xh, rowptr, col, W1, hA, N_NODES);

  // --- conv2-agg + pool (partial sums with run-length atomic flush) ---
  pool_partial<<<pool_grid, 256, 0, stream>>>(hA, col, egid, pooled);

  // --- finish: mean, dot v, sigmoid ---
  pool_finish<<<N_GRAPHS, 128, 0, stream>>>(pooled, batch, v, out);
}

// Round 6
// 215.670 us; speedup vs baseline: 1.9072x; 1.9072x over previous
//
#include <hip/hip_runtime.h>

#define N_NODES 50000
#define N_EDGES 800000
#define NF 128
#define N_GRAPHS 512
#define SCAN_BLOCKS 196   // ceil(50000/256)
#define NSPLIT 8          // edge-slices per graph in pool

union HU { ushort u; _Float16 h; };
__device__ __forceinline__ float h2f(ushort u) { HU x; x.u = u; return (float)x.h; }
__device__ __forceinline__ ushort f2h(float f) { HU x; x.h = (_Float16)f; return x.u; }

__device__ __forceinline__ void acc8(float* acc, uint4 u) {
  acc[0] += h2f((ushort)(u.x)); acc[1] += h2f((ushort)(u.x >> 16));
  acc[2] += h2f((ushort)(u.y)); acc[3] += h2f((ushort)(u.y >> 16));
  acc[4] += h2f((ushort)(u.z)); acc[5] += h2f((ushort)(u.z >> 16));
  acc[6] += h2f((ushort)(u.w)); acc[7] += h2f((ushort)(u.w >> 16));
}

// ---------------- x (f32) -> xh (fp16) ---------------------------------------
__global__ __launch_bounds__(256) void xcvt(const float* __restrict__ x,
                                            ushort* __restrict__ xh) {
  int i = blockIdx.x * 256 + threadIdx.x;
  float4 v = ((const float4*)x)[i];
  ushort4 o;
  o.x = f2h(v.x); o.y = f2h(v.y); o.z = f2h(v.z); o.w = f2h(v.w);
  ((ushort4*)xh)[i] = o;
}

// ---------------- v[f] = sum_j W2[f][j] * Wfc[j] ------------------------------
__global__ __launch_bounds__(128) void w2wfc(const float* __restrict__ W2,
                                             const float* __restrict__ Wfc,
                                             float* __restrict__ v) {
  int f = threadIdx.x;
  float s = 0.f;
  for (int j = 0; j < 128; j += 4) {
    float4 w = ((const float4*)(W2 + f * 128))[j >> 2];
    float4 c = ((const float4*)Wfc)[j >> 2];
    s += w.x * c.x + w.y * c.y + w.z * c.z + w.w * c.w;
  }
  v[f] = s;
}

// ---------------- CSR build: dst -> list of src ------------------------------
__global__ __launch_bounds__(256) void hist_kernel(const int* __restrict__ dst,
                                                   int* __restrict__ deg) {
  unsigned e = blockIdx.x * 256u + threadIdx.x;
  if (e < N_EDGES) atomicAdd(&deg[dst[e]], 1);
}

__device__ __forceinline__ int block_incl_scan_256(int v, int* warp_sums) {
  const int tid = threadIdx.x;
  const int lane = tid & 63;
  const int w = tid >> 6;
#pragma unroll
  for (int off = 1; off < 64; off <<= 1) {
    int t = __shfl_up(v, off, 64);
    if (lane >= off) v += t;
  }
  if (lane == 63) warp_sums[w] = v;
  __syncthreads();
  int ws = 0;
#pragma unroll
  for (int i = 0; i < 4; ++i) ws += (i < w) ? warp_sums[i] : 0;
  return v + ws;
}

__global__ __launch_bounds__(256) void scan_stage1(const int* __restrict__ deg,
                                                   int* __restrict__ rowptr,
                                                   int* __restrict__ blocksum) {
  __shared__ int warp_sums[4];
  int i = blockIdx.x * 256 + threadIdx.x;
  int v = (i < N_NODES) ? deg[i] : 0;
  int incl = block_incl_scan_256(v, warp_sums);
  if (i < N_NODES) rowptr[i + 1] = incl;
  if (threadIdx.x == 255) blocksum[blockIdx.x] = incl;
}

__global__ __launch_bounds__(256) void scan_stage2(int* __restrict__ blocksum) {
  __shared__ int warp_sums[4];
  int tid = threadIdx.x;
  int v = (tid < SCAN_BLOCKS) ? blocksum[tid] : 0;
  int incl = block_incl_scan_256(v, warp_sums);
  if (tid < SCAN_BLOCKS) blocksum[tid] = incl - v;
}

__global__ __launch_bounds__(256) void scan_stage3(int* __restrict__ rowptr,
                                                   const int* __restrict__ blocksum,
                                                   int* __restrict__ cursor) {
  int i = blockIdx.x * 256 + threadIdx.x;
  if (i < N_NODES) {
    int r = rowptr[i + 1] + blocksum[blockIdx.x];
    rowptr[i + 1] = r;
    cursor[i + 1] = r;
  }
  if (i == 0) { rowptr[0] = 0; cursor[0] = 0; }
}

__global__ __launch_bounds__(256) void fill_kernel(const int* __restrict__ src,
                                                   const int* __restrict__ dst,
                                                   int* __restrict__ cursor,
                                                   int* __restrict__ col) {
  unsigned e = blockIdx.x * 256u + threadIdx.x;
  if (e < N_EDGES) {
    int d = dst[e];
    int pos = atomicAdd(&cursor[d], 1);
    col[pos] = src[e];
  }
}

// ------- gather1: agg_x[n][:] = sum_{j in CSR(n)} xh[col[j]][:]  (f32 out) ---
__global__ __launch_bounds__(256) void gather_x(const ushort* __restrict__ xh,
                                                const int* __restrict__ rowptr,
                                                const int* __restrict__ col,
                                                float* __restrict__ outf) {
  unsigned gid = blockIdx.x * 256u + threadIdx.x;
  unsigned n = gid >> 5;
  unsigned q = gid & 31u;
  if (n >= N_NODES) return;
  int j0 = rowptr[n], j1 = rowptr[n + 1];
  float4 acc = float4{0.f, 0.f, 0.f, 0.f};
  int j = j0;
  for (; j + 4 <= j1; j += 4) {
    int s0 = col[j], s1 = col[j + 1], s2 = col[j + 2], s3 = col[j + 3];
    ushort4 a = ((const ushort4*)xh)[(size_t)s0 * 32 + q];
    ushort4 b = ((const ushort4*)xh)[(size_t)s1 * 32 + q];
    ushort4 c = ((const ushort4*)xh)[(size_t)s2 * 32 + q];
    ushort4 d = ((const ushort4*)xh)[(size_t)s3 * 32 + q];
    acc.x += h2f(a.x) + h2f(b.x) + h2f(c.x) + h2f(d.x);
    acc.y += h2f(a.y) + h2f(b.y) + h2f(c.y) + h2f(d.y);
    acc.z += h2f(a.z) + h2f(b.z) + h2f(c.z) + h2f(d.z);
    acc.w += h2f(a.w) + h2f(b.w) + h2f(c.w) + h2f(d.w);
  }
  for (; j < j1; ++j) {
    int s0 = col[j];
    ushort4 a = ((const ushort4*)xh)[(size_t)s0 * 32 + q];
    acc.x += h2f(a.x); acc.y += h2f(a.y); acc.z += h2f(a.z); acc.w += h2f(a.w);
  }
  ((float4*)outf)[(size_t)n * 32 + q] = acc;
}

// -------- GEMM: hA(fp16) = relu(A[M,128] @ W[128,128]) -----------------------
__global__ __launch_bounds__(256) void gemm_relu_h(const float* __restrict__ A,
                                                   const float* __restrict__ W,
                                                   ushort* __restrict__ hA, int M) {
  __shared__ float sW[32][128];
  __shared__ float sA[64][36];
  const int tid = threadIdx.x;
  const int row0 = blockIdx.x * 64;
  const int rg = tid >> 4;
  const int cg = tid & 15;

  float4 acc[4][2];
#pragma unroll
  for (int i = 0; i < 4; ++i) {
    acc[i][0] = float4{0.f, 0.f, 0.f, 0.f};
    acc[i][1] = float4{0.f, 0.f, 0.f, 0.f};
  }

  for (int kt = 0; kt < 128; kt += 32) {
#pragma unroll
    for (int i = 0; i < 4; ++i) {
      int idx = i * 256 + tid;
      int r = idx >> 5, c4 = idx & 31;
      ((float4*)&sW[r][0])[c4] = ((const float4*)W)[(kt + r) * 32 + c4];
    }
#pragma unroll
    for (int i = 0; i < 2; ++i) {
      int idx = i * 256 + tid;
      int r = idx >> 3, c4 = idx & 7;
      int gr = row0 + r;
      float4 v = float4{0.f, 0.f, 0.f, 0.f};
      if (gr < M) v = ((const float4*)A)[gr * 32 + (kt >> 2) + c4];
      *(float4*)&sA[r][c4 * 4] = v;
    }
    __syncthreads();

#pragma unroll
    for (int k = 0; k < 32; k += 4) {
      float4 a0 = *(const float4*)&sA[rg * 4 + 0][k];
      float4 a1 = *(const float4*)&sA[rg * 4 + 1][k];
      float4 a2 = *(const float4*)&sA[rg * 4 + 2][k];
      float4 a3 = *(const float4*)&sA[rg * 4 + 3][k];
      const float* ap0 = (const float*)&a0;
      const float* ap1 = (const float*)&a1;
      const float* ap2 = (const float*)&a2;
      const float* ap3 = (const float*)&a3;
#pragma unroll
      for (int kk = 0; kk < 4; ++kk) {
        float4 w0 = *(const float4*)&sW[k + kk][cg * 8];
        float4 w1 = *(const float4*)&sW[k + kk][cg * 8 + 4];
        float a0k = ap0[kk], a1k = ap1[kk], a2k = ap2[kk], a3k = ap3[kk];
#define FMA_ROW(I, AK)                                                         \
        acc[I][0].x += AK * w0.x; acc[I][0].y += AK * w0.y;                    \
        acc[I][0].z += AK * w0.z; acc[I][0].w += AK * w0.w;                    \
        acc[I][1].x += AK * w1.x; acc[I][1].y += AK * w1.y;                    \
        acc[I][1].z += AK * w1.z; acc[I][1].w += AK * w1.w;
        FMA_ROW(0, a0k)
        FMA_ROW(1, a1k)
        FMA_ROW(2, a2k)
        FMA_ROW(3, a3k)
#undef FMA_ROW
      }
    }
    __syncthreads();
  }

#pragma unroll
  for (int i = 0; i < 4; ++i) {
    int gr = row0 + rg * 4 + i;
    if (gr < M) {
      float4 a0 = acc[i][0], a1 = acc[i][1];
      a0.x = fmaxf(a0.x, 0.f); a0.y = fmaxf(a0.y, 0.f);
      a0.z = fmaxf(a0.z, 0.f); a0.w = fmaxf(a0.w, 0.f);
      a1.x = fmaxf(a1.x, 0.f); a1.y = fmaxf(a1.y, 0.f);
      a1.z = fmaxf(a1.z, 0.f); a1.w = fmaxf(a1.w, 0.f);
      uint4 o;
      o.x = (uint)f2h(a0.x) | ((uint)f2h(a0.y) << 16);
      o.y = (uint)f2h(a0.z) | ((uint)f2h(a0.w) << 16);
      o.z = (uint)f2h(a1.x) | ((uint)f2h(a1.y) << 16);
      o.w = (uint)f2h(a1.z) | ((uint)f2h(a1.w) << 16);
      ((uint4*)hA)[gr * 16 + cg] = o;
    }
  }
}

// ------- pool split: poolpart[s][g][:] = sum over slice s of graph g's edges
// of hA[col[j]][:].  No atomics: each block owns a private output slot.
// Slices are within one graph's contiguous CSR edge range (batch sorted).
__global__ __launch_bounds__(256) void pool_split(const ushort* __restrict__ hA,
                                                  const int* __restrict__ rowptr,
                                                  const int* __restrict__ col,
                                                  const int* __restrict__ batch,
                                                  float* __restrict__ poolpart) {
  __shared__ float part[16][132];
  const int g = blockIdx.x;
  const int s = blockIdx.y;
  const int q = threadIdx.x & 15;
  const int eo = threadIdx.x >> 4;

  int lo = 0, hi = N_NODES;
  while (lo < hi) { int m = (lo + hi) >> 1; if (batch[m] < g) lo = m + 1; else hi = m; }
  int s0 = lo;
  lo = 0; hi = N_NODES;
  while (lo < hi) { int m = (lo + hi) >> 1; if (batch[m] <= g) lo = m + 1; else hi = m; }
  int s1 = lo;

  int j0 = rowptr[s0], j1 = rowptr[s1];
  int len = j1 - j0;
  int a = j0 + (int)(((long long)len * s) / NSPLIT);
  int b = j0 + (int)(((long long)len * (s + 1)) / NSPLIT);

  float acc[8] = {0.f, 0.f, 0.f, 0.f, 0.f, 0.f, 0.f, 0.f};
  for (int j = a + eo; j < b; j += 16) {
    uint4 u = ((const uint4*)hA)[(size_t)col[j] * 16 + q];
    acc8(acc, u);
  }
#pragma unroll
  for (int k = 0; k < 8; ++k) part[eo][q * 8 + k] = acc[k];
  __syncthreads();

  if (threadIdx.x < 128) {
    int f = threadIdx.x;
    float ss = 0.f;
#pragma unroll
    for (int i = 0; i < 16; ++i) ss += part[i][f];
    poolpart[((size_t)s * N_GRAPHS + g) * NF + f] = ss;
  }
}

// ------- finish: z[g] = (sum_s poolpart[s][g] / cnt) . v ; sigmoid -----------
__global__ __launch_bounds__(128) void pool_finish(const float* __restrict__ poolpart,
                                                   const int* __restrict__ batch,
                                                   const float* __restrict__ v,
                                                   float* __restrict__ out) {
  __shared__ float reds[2];
  int g = blockIdx.x, f = threadIdx.x;

  int lo = 0, hi = N_NODES;
  while (lo < hi) { int m = (lo + hi) >> 1; if (batch[m] < g) lo = m + 1; else hi = m; }
  int s0 = lo;
  lo = 0; hi = N_NODES;
  while (lo < hi) { int m = (lo + hi) >> 1; if (batch[m] <= g) lo = m + 1; else hi = m; }
  int s1 = lo;

  float ss = 0.f;
#pragma unroll
  for (int i = 0; i < NSPLIT; ++i)
    ss += poolpart[((size_t)i * N_GRAPHS + g) * NF + f];

  float cnt = fmaxf((float)(s1 - s0), 1.0f);
  float z = (ss / cnt) * v[f];
#pragma unroll
  for (int off = 32; off > 0; off >>= 1) z += __shfl_down(z, off, 64);
  if (f == 0) reds[0] = z;
  if (f == 64) reds[1] = z;
  __syncthreads();
  if (f == 0) {
    float zz = reds[0] + reds[1];
    out[g] = 1.0f / (1.0f + expf(-zz));
  }
}

extern "C" void kernel_launch(void* const* d_in, const int* in_sizes, int n_in,
                              void* d_out, int out_size, void* d_ws, size_t ws_size,
                              hipStream_t stream) {
  const float* x   = (const float*)d_in[0];
  const int*   ei  = (const int*)d_in[1];
  const int*   src = ei;               // edge_index[0]
  const int*   dst = ei + N_EDGES;     // edge_index[1]
  const int* batch = (const int*)d_in[2];
  const float* W1  = (const float*)d_in[3];
  const float* W2  = (const float*)d_in[4];
  const float* Wfc = (const float*)d_in[5];
  float* out = (float*)d_out;

  float*  bufA = (float*)d_ws;                           // 6.4M f32 (agg_x)
  ushort* xh   = (ushort*)(bufA + (size_t)N_NODES * NF); // 6.4M fp16
  ushort* hA   = xh + (size_t)N_NODES * NF;              // 6.4M fp16
  float* poolpart = (float*)(hA + (size_t)N_NODES * NF); // NSPLIT*512*128 f32
  int* deg     = (int*)(poolpart + (size_t)NSPLIT * N_GRAPHS * NF);
  int* rowptr  = deg + N_NODES;          // N_NODES+1
  int* cursor  = rowptr + N_NODES + 1;   // N_NODES+1
  int* col     = cursor + N_NODES + 1;   // N_EDGES
  int* blocksum = col + N_EDGES;         // SCAN_BLOCKS
  float* v     = (float*)(blocksum + SCAN_BLOCKS + 4);   // 128

  const int gemm_grid = (N_NODES + 63) / 64;            // 782
  const int edge_grid = (N_EDGES + 255) / 256;          // 3125
  const int agg_grid  = (N_NODES * 32 + 255) / 256;     // 6250
  const int cvt_grid  = (N_NODES * NF / 4) / 256;       // 6250 exact

  // --- build CSR (dst -> srcs) ---
  hipMemsetAsync(deg, 0, N_NODES * sizeof(int), stream);
  hist_kernel<<<edge_grid, 256, 0, stream>>>(dst, deg);
  scan_stage1<<<SCAN_BLOCKS, 256, 0, stream>>>(deg, rowptr, blocksum);
  scan_stage2<<<1, 256, 0, stream>>>(blocksum);
  scan_stage3<<<SCAN_BLOCKS, 256, 0, stream>>>(rowptr, blocksum, cursor);
  fill_kernel<<<edge_grid, 256, 0, stream>>>(src, dst, cursor, col);

  // --- precompute fp16 x and v = W2@Wfc ---
  xcvt<<<cvt_grid, 256, 0, stream>>>(x, xh);
  w2wfc<<<1, 128, 0, stream>>>(W2, Wfc, v);

  // --- conv1: agg_x = gather(xh); hA = relu(agg_x @ W1) (fp16) ---
  gather_x<<<agg_grid, 256, 0, stream>>>(xh, rowptr, col, bufA);
  gemm_relu_h<<<gemm_grid, 256, 0, stream>>>(bufA, W1, hA, N_NODES);

  // --- conv2-agg + pool: per-(graph,slice) private partial sums, no atomics --
  pool_split<<<dim3(N_GRAPHS, NSPLIT), 256, 0, stream>>>(hA, rowptr, col, batch,
                                                         poolpart);
  pool_finish<<<N_GRAPHS, 128, 0, stream>>>(poolpart, batch, v, out);
}